// Round 6
// baseline (490.030 us; speedup 1.0000x reference)
//
#include <hip/hip_runtime.h>
#include <cstdint>
#include <cstddef>

#define B_ROWS 16384
#define DIMSZ  1024
#define NH     8
#define HD     128
#define KDIM   1024

typedef __attribute__((ext_vector_type(8))) __bf16 bf16x8;
typedef __attribute__((ext_vector_type(4))) float f32x4;
typedef __attribute__((ext_vector_type(8))) unsigned short ushort8v;

__device__ __forceinline__ unsigned short f2bf(float f) {
  union { float f; unsigned int u; } x; x.f = f;
  unsigned int r = x.u + 0x7FFFu + ((x.u >> 16) & 1u);   // RNE
  return (unsigned short)(r >> 16);
}
__device__ __forceinline__ float bf2f(unsigned short h) {
  union { unsigned int u; float f; } x; x.u = ((unsigned int)h) << 16;
  return x.f;
}

__device__ __forceinline__ void gload_lds16(const void* g, void* l) {
  __builtin_amdgcn_global_load_lds(
      (__attribute__((address_space(1))) void*)(uintptr_t)g,
      (__attribute__((address_space(3))) void*)(uintptr_t)l, 16, 0, 0);
}

// ---------------- fp32 -> bf16 convert (both features, one launch) -----------
__global__ __launch_bounds__(256) void cvt2_k(const float* __restrict__ a,
                                              const float* __restrict__ b,
                                              unsigned short* __restrict__ oa,
                                              unsigned short* __restrict__ ob,
                                              int n8each) {
  int i = blockIdx.x * 256 + threadIdx.x;
  const float* src; unsigned short* dst; int j;
  if (i < n8each) { src = a; dst = oa; j = i; }
  else            { src = b; dst = ob; j = i - n8each; }
  const float4* p = (const float4*)src + 2 * (size_t)j;
  float4 x = p[0], y = p[1];
  ushort8v o;
  o[0] = f2bf(x.x); o[1] = f2bf(x.y); o[2] = f2bf(x.z); o[3] = f2bf(x.w);
  o[4] = f2bf(y.x); o[5] = f2bf(y.y); o[6] = f2bf(y.z); o[7] = f2bf(y.w);
  *(ushort8v*)(dst + 8 * (size_t)j) = o;
}

// ---------------- all 4 weight transposes, one launch ------------------------
__global__ __launch_bounds__(256) void transpose_cvt4_k(
    const float* __restrict__ W0, const float* __restrict__ W1,
    const float* __restrict__ W2, const float* __restrict__ W3,
    unsigned short* __restrict__ T0, unsigned short* __restrict__ T1,
    unsigned short* __restrict__ T2, unsigned short* __restrict__ T3) {
  const float* W; unsigned short* T;
  switch (blockIdx.z) {
    case 0: W = W0; T = T0; break;
    case 1: W = W1; T = T1; break;
    case 2: W = W2; T = T2; break;
    default: W = W3; T = T3; break;
  }
  __shared__ float tile[32][33];
  int bx = blockIdx.x * 32, by = blockIdx.y * 32;
  int tx = threadIdx.x & 31, ty = threadIdx.x >> 5;
  #pragma unroll
  for (int j = ty; j < 32; j += 8)
    tile[j][tx] = W[(size_t)(by + j) * DIMSZ + bx + tx];
  __syncthreads();
  #pragma unroll
  for (int j = ty; j < 32; j += 8)
    T[(size_t)(bx + j) * DIMSZ + by + tx] = f2bf(tile[tx][j]);
}

// ---------------- bf16 MFMA GEMM, 128x128 tile, 4 blocks/CU ------------------
// C[M,NCOLS] = A[M,K] @ Bt[NCOLS,K]^T + bias.
// BM=BN=128, BK=64, 4 waves (2x2), per-wave 64x64, acc[4][4].
// Single 32 KB LDS buffer, 2 __syncthreads per K-tile (m97 structure);
// stage(t+1) issued BEFORE the 32-MFMA cluster; cross-block overlap
// (4 blocks/CU) covers the barrier drains.  0-conflict XOR swizzle
// c' = c ^ (row&7) on 16B chunks (R4/R5-proven), staged via inverse-permuted
// global source (rule #21).  T1 XCD swizzle.  Split epilogue for fused KV.
// Epilogue stages the C tile through LDS so global stores are fully
// coalesced 16B/lane linear streams (R5 showed fp32 strided stores cost
// the O GEMM ~33 us).
template <int NCOLS, int OUT_BF16>
__global__ __launch_bounds__(256, 4) void gemm6_k(
    const unsigned short* __restrict__ A,
    const unsigned short* __restrict__ Bt,
    const float* __restrict__ bias0, const float* __restrict__ bias1,
    void* __restrict__ out0, void* __restrict__ out1) {
  constexpr int NBC = NCOLS / 128;
  constexpr int NWG = (B_ROWS / 128) * NBC;
  constexpr int NKT = KDIM / 64;   // 16

  __shared__ __align__(16) char smem[32768];   // A tile | B tile; C tile in epilogue
  char* Asm = smem;
  char* Bsm = smem + 16384;

  const int tid = threadIdx.x;
  const int wid = tid >> 6, lane = tid & 63;
  const int lr = lane & 15, kg = lane >> 4;
  const int wr = wid >> 1, wc = wid & 1;
  const int swz = lr & 7;

  // T1: XCD-aware block swizzle (NWG % 8 == 0 for all instantiations)
  const int x = ((int)blockIdx.x % 8) * (NWG / 8) + (int)blockIdx.x / 8;
  const int bcol = (x % NBC) * 128;
  const int brow = (x / NBC) * 128;

  const char* Ab = (const char*)(A + (size_t)brow * KDIM);
  const char* Bb = (const char*)(Bt + (size_t)bcol * KDIM);

  // staging: 4 rounds x 4KB per operand; dest byte D = j*4096 + tid*16
  // (linear); source applies inverse swizzle.
  int soff[4];
  #pragma unroll
  for (int j = 0; j < 4; ++j) {
    int D = j * 4096 + tid * 16;
    int row = D >> 7, c = (D >> 4) & 7;
    soff[j] = row * 2048 + ((c ^ (row & 7)) << 4);
  }

  auto stage = [&](int t) {
    #pragma unroll
    for (int j = 0; j < 4; ++j) {
      gload_lds16(Ab + (size_t)soff[j] + t * 128, Asm + j * 4096 + tid * 16);
      gload_lds16(Bb + (size_t)soff[j] + t * 128, Bsm + j * 4096 + tid * 16);
    }
  };

  f32x4 acc[4][4] = {};
  stage(0);

  #pragma unroll 1
  for (int t = 0; t < NKT; ++t) {
    __syncthreads();   // stage(t) landed (drains vmcnt chip-wide)

    bf16x8 af[4][2], bfr[4][2];
    #pragma unroll
    for (int m = 0; m < 4; ++m) {
      int row = wr * 64 + m * 16 + lr;
      #pragma unroll
      for (int kk = 0; kk < 2; ++kk)
        af[m][kk] = *(const bf16x8*)(Asm + row * 128 + (((kk * 4 + kg) ^ swz) << 4));
    }
    #pragma unroll
    for (int n = 0; n < 4; ++n) {
      int row = wc * 64 + n * 16 + lr;
      #pragma unroll
      for (int kk = 0; kk < 2; ++kk)
        bfr[n][kk] = *(const bf16x8*)(Bsm + row * 128 + (((kk * 4 + kg) ^ swz) << 4));
    }
    __syncthreads();   // all waves' reads done -> safe to overwrite

    if (t + 1 < NKT) stage(t + 1);   // latency hides under the MFMAs below

    __builtin_amdgcn_s_setprio(1);
    #pragma unroll
    for (int m = 0; m < 4; ++m)
      #pragma unroll
      for (int n = 0; n < 4; ++n) {
        acc[m][n] = __builtin_amdgcn_mfma_f32_16x16x32_bf16(af[m][0], bfr[n][0], acc[m][n], 0, 0, 0);
        acc[m][n] = __builtin_amdgcn_mfma_f32_16x16x32_bf16(af[m][1], bfr[n][1], acc[m][n], 0, 0, 0);
      }
    __builtin_amdgcn_s_setprio(0);
  }

  // ---- epilogue: LDS-staged coalesced stores ----
  // After the K-loop's final (read-)syncthreads no wave touches Asm/Bsm again,
  // so the 32 KB buffer is reusable without an extra barrier before writes.
  const float* bias; char* outp; int ocol0;
  if (NCOLS == 1024 || bcol < 1024) { bias = bias0; outp = (char*)out0; ocol0 = bcol; }
  else                              { bias = bias1; outp = (char*)out1; ocol0 = bcol - 1024; }

  constexpr int ESZ  = OUT_BF16 ? 2 : 4;
  constexpr int RPP  = OUT_BF16 ? 128 : 64;   // rows per pass (32 KB each)
  constexpr int NPAS = 128 / RPP;
  constexpr int ROWB = 128 * ESZ;             // bytes per tile row

  #pragma unroll
  for (int p = 0; p < NPAS; ++p) {
    // write my acc rows (+bias) into the LDS C-tile
    if (NPAS == 1 || wr == p) {
      #pragma unroll
      for (int n = 0; n < 4; ++n) {
        int col = wc * 64 + n * 16 + lr;
        float bb = bias[ocol0 + col];
        #pragma unroll
        for (int m = 0; m < 4; ++m)
          #pragma unroll
          for (int r = 0; r < 4; ++r) {
            int rl = m * 16 + kg * 4 + r;                 // 0..63 within wave half
            int row = (NPAS == 1) ? (wr * 64 + rl) : rl;  // LDS row
            float v = acc[m][n][r] + bb;
            if (OUT_BF16) ((unsigned short*)smem)[row * 128 + col] = f2bf(v);
            else          ((float*)smem)[row * 128 + col] = v;
          }
      }
    }
    __syncthreads();
    // cooperative linear store: 32 KB per pass, 16 B/lane, fully coalesced
    #pragma unroll
    for (int i = 0; i < 8; ++i) {
      int off = i * 4096 + tid * 16;
      int row = off / ROWB, colb = off % ROWB;
      char* gp = outp + ((size_t)(brow + p * RPP + row) * 1024 + ocol0) * ESZ + colb;
      *(float4*)gp = *(const float4*)(smem + off);
    }
    if (p + 1 < NPAS) __syncthreads();
  }
}

// ---------------- per-sample 8x8 cross-head attention ------------------------
__global__ __launch_bounds__(256) void attn_k(const unsigned short* __restrict__ Q,
                                              const unsigned short* __restrict__ Kc,
                                              const unsigned short* __restrict__ V,
                                              unsigned short* __restrict__ ctx) {
  __shared__ __align__(16) unsigned short sm[4][3][NH][136];
  const int wid = threadIdx.x >> 6, lane = threadIdx.x & 63;
  const int b = (blockIdx.x << 2) + wid;

  const unsigned short* bases[3] = { Q + (size_t)b * DIMSZ,
                                     Kc + (size_t)b * DIMSZ,
                                     V + (size_t)b * DIMSZ };
  const int row = lane >> 3, ch = lane & 7;
  #pragma unroll
  for (int m = 0; m < 3; ++m) {
    ushort8v v0 = *(const ushort8v*)(bases[m] + row * HD + ch * 16);
    ushort8v v1 = *(const ushort8v*)(bases[m] + row * HD + ch * 16 + 8);
    *(ushort8v*)&sm[wid][m][row][ch * 16] = v0;
    *(ushort8v*)&sm[wid][m][row][ch * 16 + 8] = v1;
  }
  __syncthreads();

  const int h = lane >> 3, g = lane & 7;
  const unsigned short* qr = &sm[wid][0][h][0];
  const unsigned short* kr = &sm[wid][1][g][0];
  float s = 0.f;
  #pragma unroll
  for (int c = 0; c < 16; ++c) {
    ushort8v qv = *(const ushort8v*)(qr + c * 8);
    ushort8v kv = *(const ushort8v*)(kr + c * 8);
    #pragma unroll
    for (int j = 0; j < 8; ++j) s += bf2f(qv[j]) * bf2f(kv[j]);
  }
  s *= 0.088388347648318447f;

  float mx = s;
  #pragma unroll
  for (int o = 1; o < 8; o <<= 1) mx = fmaxf(mx, __shfl_xor(mx, o));
  float e = __expf(s - mx);
  float sum = e;
  #pragma unroll
  for (int o = 1; o < 8; o <<= 1) sum += __shfl_xor(sum, o);
  float attn = e / sum;

  const int h2 = lane >> 3, d0 = (lane & 7) * 16;
  float cacc[16];
  #pragma unroll
  for (int j = 0; j < 16; ++j) cacc[j] = 0.f;
  #pragma unroll
  for (int g2 = 0; g2 < 8; ++g2) {
    float a = __shfl(attn, (lane & 56) + g2);
    const unsigned short* vr = &sm[wid][2][g2][d0];
    ushort8v v0 = *(const ushort8v*)vr;
    ushort8v v1 = *(const ushort8v*)(vr + 8);
    #pragma unroll
    for (int j = 0; j < 8; ++j) {
      cacc[j]     += a * bf2f(v0[j]);
      cacc[8 + j] += a * bf2f(v1[j]);
    }
  }
  ushort8v o0, o1;
  #pragma unroll
  for (int j = 0; j < 8; ++j) { o0[j] = f2bf(cacc[j]); o1[j] = f2bf(cacc[8 + j]); }
  unsigned short* op = ctx + (size_t)b * DIMSZ + h2 * HD + d0;
  *(ushort8v*)op = o0;
  *(ushort8v*)(op + 8) = o1;
}

// ---------------- launcher ---------------------------------------------------
extern "C" void kernel_launch(void* const* d_in, const int* in_sizes, int n_in,
                              void* d_out, int out_size, void* d_ws, size_t ws_size,
                              hipStream_t stream) {
  const float* feat1 = (const float*)d_in[0];
  const float* feat2 = (const float*)d_in[1];
  const float* Wq = (const float*)d_in[2];
  const float* bq = (const float*)d_in[3];
  const float* Wk = (const float*)d_in[4];
  const float* bk = (const float*)d_in[5];
  const float* Wv = (const float*)d_in[6];
  const float* bv = (const float*)d_in[7];
  const float* Wo = (const float*)d_in[8];
  const float* bo = (const float*)d_in[9];
  float* out = (float*)d_out;

  const int M = B_ROWS;
  char* ws = (char*)d_ws;
  const size_t featB = (size_t)M * DIMSZ * 2;   // 32 MB
  const size_t wB = (size_t)DIMSZ * DIMSZ * 2;  // 2 MB
  unsigned short* f1b = (unsigned short*)(ws);
  unsigned short* f2b = (unsigned short*)(ws + featB);
  unsigned short* Qb  = (unsigned short*)(ws + 2 * featB);
  unsigned short* Kb  = (unsigned short*)(ws + 3 * featB);
  unsigned short* Vb  = (unsigned short*)(ws + 4 * featB);
  unsigned short* Wqt = (unsigned short*)(ws + 5 * featB);
  unsigned short* Wkt = (unsigned short*)(ws + 5 * featB + wB);   // Wkt,Wvt adjacent
  unsigned short* Wvt = (unsigned short*)(ws + 5 * featB + 2 * wB);
  unsigned short* Wot = (unsigned short*)(ws + 5 * featB + 3 * wB);
  unsigned short* ctx = f1b;   // f1b dead after Q GEMM

  const int n8 = M * DIMSZ / 8;
  cvt2_k<<<(2 * n8 + 255) / 256, 256, 0, stream>>>(feat1, feat2, f1b, f2b, n8);
  transpose_cvt4_k<<<dim3(32, 32, 4), 256, 0, stream>>>(Wq, Wk, Wv, Wo,
                                                        Wqt, Wkt, Wvt, Wot);

  // Q: N=1024 (1024 blocks), KV fused: N=2048 (2048 blocks)
  gemm6_k<1024, 1><<<1024, 256, 0, stream>>>(f1b, Wqt, bq, bq, Qb, Qb);
  gemm6_k<2048, 1><<<2048, 256, 0, stream>>>(f2b, Wkt, bk, bv, Kb, Vb);

  attn_k<<<M / 4, 256, 0, stream>>>(Qb, Kb, Vb, ctx);

  // output projection: fp32 out
  gemm6_k<1024, 0><<<1024, 256, 0, stream>>>(ctx, Wot, bo, bo, out, out);
}

// Round 7
// 221.413 us; speedup vs baseline: 2.2132x; 2.2132x over previous
//
#include <hip/hip_runtime.h>
#include <cstdint>
#include <cstddef>

#define B_ROWS 16384
#define DIMSZ  1024
#define NH     8
#define HD     128
#define KDIM   1024

typedef __attribute__((ext_vector_type(8))) __bf16 bf16x8;
typedef __attribute__((ext_vector_type(4))) float f32x4;
typedef __attribute__((ext_vector_type(8))) unsigned short ushort8v;

__device__ __forceinline__ unsigned short f2bf(float f) {
  union { float f; unsigned int u; } x; x.f = f;
  unsigned int r = x.u + 0x7FFFu + ((x.u >> 16) & 1u);   // RNE
  return (unsigned short)(r >> 16);
}
__device__ __forceinline__ float bf2f(unsigned short h) {
  union { unsigned int u; float f; } x; x.u = ((unsigned int)h) << 16;
  return x.f;
}

__device__ __forceinline__ void gload_lds16(const void* g, void* l) {
  __builtin_amdgcn_global_load_lds(
      (__attribute__((address_space(1))) void*)(uintptr_t)g,
      (__attribute__((address_space(3))) void*)(uintptr_t)l, 16, 0, 0);
}

// ---------------- fp32 -> bf16 convert (both features, one launch) -----------
__global__ __launch_bounds__(256) void cvt2_k(const float* __restrict__ a,
                                              const float* __restrict__ b,
                                              unsigned short* __restrict__ oa,
                                              unsigned short* __restrict__ ob,
                                              int n8each) {
  int i = blockIdx.x * 256 + threadIdx.x;
  const float* src; unsigned short* dst; int j;
  if (i < n8each) { src = a; dst = oa; j = i; }
  else            { src = b; dst = ob; j = i - n8each; }
  const float4* p = (const float4*)src + 2 * (size_t)j;
  float4 x = p[0], y = p[1];
  ushort8v o;
  o[0] = f2bf(x.x); o[1] = f2bf(x.y); o[2] = f2bf(x.z); o[3] = f2bf(x.w);
  o[4] = f2bf(y.x); o[5] = f2bf(y.y); o[6] = f2bf(y.z); o[7] = f2bf(y.w);
  *(ushort8v*)(dst + 8 * (size_t)j) = o;
}

// ---------------- all 4 weight transposes, one launch ------------------------
__global__ __launch_bounds__(256) void transpose_cvt4_k(
    const float* __restrict__ W0, const float* __restrict__ W1,
    const float* __restrict__ W2, const float* __restrict__ W3,
    unsigned short* __restrict__ T0, unsigned short* __restrict__ T1,
    unsigned short* __restrict__ T2, unsigned short* __restrict__ T3) {
  const float* W; unsigned short* T;
  switch (blockIdx.z) {
    case 0: W = W0; T = T0; break;
    case 1: W = W1; T = T1; break;
    case 2: W = W2; T = T2; break;
    default: W = W3; T = T3; break;
  }
  __shared__ float tile[32][33];
  int bx = blockIdx.x * 32, by = blockIdx.y * 32;
  int tx = threadIdx.x & 31, ty = threadIdx.x >> 5;
  #pragma unroll
  for (int j = ty; j < 32; j += 8)
    tile[j][tx] = W[(size_t)(by + j) * DIMSZ + bx + tx];
  __syncthreads();
  #pragma unroll
  for (int j = ty; j < 32; j += 8)
    T[(size_t)(bx + j) * DIMSZ + by + tx] = f2bf(tile[tx][j]);
}

// ---------------- bf16 MFMA GEMM, 128x128 tile ------------------------------
// C[M,NCOLS] = A[M,K] @ Bt[NCOLS,K]^T + bias.
// BM=BN=128, BK=64, 4 waves (2x2), per-wave 64x64, acc[4][4].
// Single 32 KB LDS buffer, 2 __syncthreads per K-tile (m97 structure);
// stage(t+1) issued BEFORE the 32-MFMA cluster; cross-block overlap
// covers the barrier drains.  0-conflict XOR swizzle c' = c ^ (row&7) on
// 16B chunks (R4/R5-proven), staged via inverse-permuted global source.
// T1 XCD swizzle.  Split epilogue for fused KV.  Epilogue stages the C tile
// through LDS for fully-coalesced 16B/lane stores.
// NOTE: __launch_bounds__ MUST stay (256,3): (256,4) caps VGPR at 64 ->
// accumulator spills -> 455MB scratch traffic, 2.4x slower (R6 regression).
template <int NCOLS, int OUT_BF16>
__global__ __launch_bounds__(256, 3) void gemm7_k(
    const unsigned short* __restrict__ A,
    const unsigned short* __restrict__ Bt,
    const float* __restrict__ bias0, const float* __restrict__ bias1,
    void* __restrict__ out0, void* __restrict__ out1) {
  constexpr int NBC = NCOLS / 128;
  constexpr int NWG = (B_ROWS / 128) * NBC;
  constexpr int NKT = KDIM / 64;   // 16

  __shared__ __align__(16) char smem[32768];   // A tile | B tile; C tile in epilogue
  char* Asm = smem;
  char* Bsm = smem + 16384;

  const int tid = threadIdx.x;
  const int wid = tid >> 6, lane = tid & 63;
  const int lr = lane & 15, kg = lane >> 4;
  const int wr = wid >> 1, wc = wid & 1;
  const int swz = lr & 7;

  // T1: XCD-aware block swizzle (NWG % 8 == 0 for all instantiations)
  const int x = ((int)blockIdx.x % 8) * (NWG / 8) + (int)blockIdx.x / 8;
  const int bcol = (x % NBC) * 128;
  const int brow = (x / NBC) * 128;

  const char* Ab = (const char*)(A + (size_t)brow * KDIM);
  const char* Bb = (const char*)(Bt + (size_t)bcol * KDIM);

  // staging: 4 rounds x 4KB per operand; dest byte D = j*4096 + tid*16
  // (linear); source applies inverse swizzle.
  int soff[4];
  #pragma unroll
  for (int j = 0; j < 4; ++j) {
    int D = j * 4096 + tid * 16;
    int row = D >> 7, c = (D >> 4) & 7;
    soff[j] = row * 2048 + ((c ^ (row & 7)) << 4);
  }

  auto stage = [&](int t) {
    #pragma unroll
    for (int j = 0; j < 4; ++j) {
      gload_lds16(Ab + (size_t)soff[j] + t * 128, Asm + j * 4096 + tid * 16);
      gload_lds16(Bb + (size_t)soff[j] + t * 128, Bsm + j * 4096 + tid * 16);
    }
  };

  f32x4 acc[4][4] = {};
  stage(0);

  #pragma unroll 1
  for (int t = 0; t < NKT; ++t) {
    __syncthreads();   // stage(t) landed (drains vmcnt chip-wide)

    bf16x8 af[4][2], bfr[4][2];
    #pragma unroll
    for (int m = 0; m < 4; ++m) {
      int row = wr * 64 + m * 16 + lr;
      #pragma unroll
      for (int kk = 0; kk < 2; ++kk)
        af[m][kk] = *(const bf16x8*)(Asm + row * 128 + (((kk * 4 + kg) ^ swz) << 4));
    }
    #pragma unroll
    for (int n = 0; n < 4; ++n) {
      int row = wc * 64 + n * 16 + lr;
      #pragma unroll
      for (int kk = 0; kk < 2; ++kk)
        bfr[n][kk] = *(const bf16x8*)(Bsm + row * 128 + (((kk * 4 + kg) ^ swz) << 4));
    }
    __syncthreads();   // all waves' reads done -> safe to overwrite

    if (t + 1 < NKT) stage(t + 1);   // latency hides under the MFMAs below

    __builtin_amdgcn_s_setprio(1);
    #pragma unroll
    for (int m = 0; m < 4; ++m)
      #pragma unroll
      for (int n = 0; n < 4; ++n) {
        acc[m][n] = __builtin_amdgcn_mfma_f32_16x16x32_bf16(af[m][0], bfr[n][0], acc[m][n], 0, 0, 0);
        acc[m][n] = __builtin_amdgcn_mfma_f32_16x16x32_bf16(af[m][1], bfr[n][1], acc[m][n], 0, 0, 0);
      }
    __builtin_amdgcn_s_setprio(0);
  }

  // ---- epilogue: LDS-staged coalesced stores ----
  // After the K-loop's final (read-)syncthreads no wave touches Asm/Bsm again,
  // so the 32 KB buffer is reusable without an extra barrier before writes.
  const float* bias; char* outp; int ocol0;
  if (NCOLS == 1024 || bcol < 1024) { bias = bias0; outp = (char*)out0; ocol0 = bcol; }
  else                              { bias = bias1; outp = (char*)out1; ocol0 = bcol - 1024; }

  constexpr int ESZ  = OUT_BF16 ? 2 : 4;
  constexpr int RPP  = OUT_BF16 ? 128 : 64;   // rows per pass (32 KB each)
  constexpr int NPAS = 128 / RPP;
  constexpr int ROWB = 128 * ESZ;             // bytes per tile row

  #pragma unroll
  for (int p = 0; p < NPAS; ++p) {
    // write my acc rows (+bias) into the LDS C-tile
    if (NPAS == 1 || wr == p) {
      #pragma unroll
      for (int n = 0; n < 4; ++n) {
        int col = wc * 64 + n * 16 + lr;
        float bb = bias[ocol0 + col];
        #pragma unroll
        for (int m = 0; m < 4; ++m)
          #pragma unroll
          for (int r = 0; r < 4; ++r) {
            int rl = m * 16 + kg * 4 + r;                 // 0..63 within wave half
            int row = (NPAS == 1) ? (wr * 64 + rl) : rl;  // LDS row
            float v = acc[m][n][r] + bb;
            if (OUT_BF16) ((unsigned short*)smem)[row * 128 + col] = f2bf(v);
            else          ((float*)smem)[row * 128 + col] = v;
          }
      }
    }
    __syncthreads();
    // cooperative linear store: 32 KB per pass, 16 B/lane, fully coalesced
    #pragma unroll
    for (int i = 0; i < 8; ++i) {
      int off = i * 4096 + tid * 16;
      int row = off / ROWB, colb = off % ROWB;
      char* gp = outp + ((size_t)(brow + p * RPP + row) * 1024 + ocol0) * ESZ + colb;
      *(float4*)gp = *(const float4*)(smem + off);
    }
    if (p + 1 < NPAS) __syncthreads();
  }
}

// ---------------- per-sample 8x8 cross-head attention ------------------------
__global__ __launch_bounds__(256) void attn_k(const unsigned short* __restrict__ Q,
                                              const unsigned short* __restrict__ Kc,
                                              const unsigned short* __restrict__ V,
                                              unsigned short* __restrict__ ctx) {
  __shared__ __align__(16) unsigned short sm[4][3][NH][136];
  const int wid = threadIdx.x >> 6, lane = threadIdx.x & 63;
  const int b = (blockIdx.x << 2) + wid;

  const unsigned short* bases[3] = { Q + (size_t)b * DIMSZ,
                                     Kc + (size_t)b * DIMSZ,
                                     V + (size_t)b * DIMSZ };
  const int row = lane >> 3, ch = lane & 7;
  #pragma unroll
  for (int m = 0; m < 3; ++m) {
    ushort8v v0 = *(const ushort8v*)(bases[m] + row * HD + ch * 16);
    ushort8v v1 = *(const ushort8v*)(bases[m] + row * HD + ch * 16 + 8);
    *(ushort8v*)&sm[wid][m][row][ch * 16] = v0;
    *(ushort8v*)&sm[wid][m][row][ch * 16 + 8] = v1;
  }
  __syncthreads();

  const int h = lane >> 3, g = lane & 7;
  const unsigned short* qr = &sm[wid][0][h][0];
  const unsigned short* kr = &sm[wid][1][g][0];
  float s = 0.f;
  #pragma unroll
  for (int c = 0; c < 16; ++c) {
    ushort8v qv = *(const ushort8v*)(qr + c * 8);
    ushort8v kv = *(const ushort8v*)(kr + c * 8);
    #pragma unroll
    for (int j = 0; j < 8; ++j) s += bf2f(qv[j]) * bf2f(kv[j]);
  }
  s *= 0.088388347648318447f;

  float mx = s;
  #pragma unroll
  for (int o = 1; o < 8; o <<= 1) mx = fmaxf(mx, __shfl_xor(mx, o));
  float e = __expf(s - mx);
  float sum = e;
  #pragma unroll
  for (int o = 1; o < 8; o <<= 1) sum += __shfl_xor(sum, o);
  float attn = e / sum;

  const int h2 = lane >> 3, d0 = (lane & 7) * 16;
  float cacc[16];
  #pragma unroll
  for (int j = 0; j < 16; ++j) cacc[j] = 0.f;
  #pragma unroll
  for (int g2 = 0; g2 < 8; ++g2) {
    float a = __shfl(attn, (lane & 56) + g2);
    const unsigned short* vr = &sm[wid][2][g2][d0];
    ushort8v v0 = *(const ushort8v*)vr;
    ushort8v v1 = *(const ushort8v*)(vr + 8);
    #pragma unroll
    for (int j = 0; j < 8; ++j) {
      cacc[j]     += a * bf2f(v0[j]);
      cacc[8 + j] += a * bf2f(v1[j]);
    }
  }
  ushort8v o0, o1;
  #pragma unroll
  for (int j = 0; j < 8; ++j) { o0[j] = f2bf(cacc[j]); o1[j] = f2bf(cacc[8 + j]); }
  unsigned short* op = ctx + (size_t)b * DIMSZ + h2 * HD + d0;
  *(ushort8v*)op = o0;
  *(ushort8v*)(op + 8) = o1;
}

// ---------------- launcher ---------------------------------------------------
extern "C" void kernel_launch(void* const* d_in, const int* in_sizes, int n_in,
                              void* d_out, int out_size, void* d_ws, size_t ws_size,
                              hipStream_t stream) {
  const float* feat1 = (const float*)d_in[0];
  const float* feat2 = (const float*)d_in[1];
  const float* Wq = (const float*)d_in[2];
  const float* bq = (const float*)d_in[3];
  const float* Wk = (const float*)d_in[4];
  const float* bk = (const float*)d_in[5];
  const float* Wv = (const float*)d_in[6];
  const float* bv = (const float*)d_in[7];
  const float* Wo = (const float*)d_in[8];
  const float* bo = (const float*)d_in[9];
  float* out = (float*)d_out;

  const int M = B_ROWS;
  char* ws = (char*)d_ws;
  const size_t featB = (size_t)M * DIMSZ * 2;   // 32 MB
  const size_t wB = (size_t)DIMSZ * DIMSZ * 2;  // 2 MB
  unsigned short* f1b = (unsigned short*)(ws);
  unsigned short* f2b = (unsigned short*)(ws + featB);
  unsigned short* Qb  = (unsigned short*)(ws + 2 * featB);
  unsigned short* Kb  = (unsigned short*)(ws + 3 * featB);
  unsigned short* Vb  = (unsigned short*)(ws + 4 * featB);
  unsigned short* Wqt = (unsigned short*)(ws + 5 * featB);
  unsigned short* Wkt = (unsigned short*)(ws + 5 * featB + wB);   // Wkt,Wvt adjacent
  unsigned short* Wvt = (unsigned short*)(ws + 5 * featB + 2 * wB);
  unsigned short* Wot = (unsigned short*)(ws + 5 * featB + 3 * wB);
  unsigned short* ctx = f1b;   // f1b dead after Q GEMM

  const int n8 = M * DIMSZ / 8;
  cvt2_k<<<(2 * n8 + 255) / 256, 256, 0, stream>>>(feat1, feat2, f1b, f2b, n8);
  transpose_cvt4_k<<<dim3(32, 32, 4), 256, 0, stream>>>(Wq, Wk, Wv, Wo,
                                                        Wqt, Wkt, Wvt, Wot);

  // Q: N=1024 (1024 blocks), KV fused: N=2048 (2048 blocks)
  gemm7_k<1024, 1><<<1024, 256, 0, stream>>>(f1b, Wqt, bq, bq, Qb, Qb);
  gemm7_k<2048, 1><<<2048, 256, 0, stream>>>(f2b, Wkt, bk, bv, Kb, Vb);

  attn_k<<<M / 4, 256, 0, stream>>>(Qb, Kb, Vb, ctx);

  // output projection: fp32 out
  gemm7_k<1024, 0><<<1024, 256, 0, stream>>>(ctx, Wot, bo, bo, out, out);
}